// Round 3
// baseline (71.857 us; speedup 1.0000x reference)
//
#include <hip/hip_runtime.h>
#include <hip/hip_bf16.h>

// NeRFDecoderHead: ray-marched occupancy render. ALL I/O is float32.
//   inputs: rays_o (R,3), rays_d (R,3), voxel (1,200,200,16), rgb_recon (3,200,200,16)
//   output: depth (R) ++ rgb_marched (R,3), flat float32.
//
// Algorithmic notes:
//  * probs = diff(min(cumsum(p_raw),1)) with p_raw = inside ? sigmoid(dens) : 0,
//    and p_raw[last] = inside ? sig : 1.  Saturating scan => once running raw
//    sum c >= 1, all later probs are exactly 0 -> early break (densities
//    ~N(0,1) => sigmoid~0.5 => saturation in ~2-3 samples, ~100x work cut).
//  * Ray origins are strictly inside the bbox and the bbox is convex, so the
//    inside-set along the ray is a prefix of samples; at first outside sample
//    only the forced last sample remains: depth += (1-min(c,1))*z_last.
//  * Trilinear weights computed once per sample, reused for density + 3 rgb
//    channels; accumulation order matches the reference (000..111).

namespace {
constexpr int DX = 200, DY = 200, DZ = 16;
constexpr int GRID_N = DX * DY * DZ;   // 640000 per channel
constexpr int NS = 287;                // N_SAMPLES
constexpr float ZSTEP = 0.2f;          // stepsize(0.5) * voxel_size(0.4)
} // namespace

extern "C" __global__ void __launch_bounds__(256)
nerf_march_kernel(const float* __restrict__ ro,
                  const float* __restrict__ rd,
                  const float* __restrict__ vox,
                  const float* __restrict__ rgbg,
                  float* __restrict__ out, int R)
{
    const int r = blockIdx.x * blockDim.x + threadIdx.x;
    if (r >= R) return;

    const float ox = ro[3 * r + 0];
    const float oy = ro[3 * r + 1];
    const float oz = ro[3 * r + 2];
    const float dx = rd[3 * r + 0];
    const float dy = rd[3 * r + 1];
    const float dz = rd[3 * r + 2];

    float c = 0.0f;                 // running (unclamped) cumsum of probs_raw
    float depth = 0.0f;
    float a0 = 0.0f, a1 = 0.0f, a2 = 0.0f;
    const float zlast = ZSTEP * (float)(NS - 1);   // 57.2

    #pragma unroll 1
    for (int n = 0; n < NS; ++n) {
        const float z  = ZSTEP * (float)n;
        const float px = ox + dx * z;
        const float py = oy + dy * z;
        const float pz = oz + dz * z;

        const bool inside = (px >= -40.0f) & (px <= 40.0f) &
                            (py >= -40.0f) & (py <= 40.0f) &
                            (pz >= -1.0f)  & (pz <= 5.4f);
        if (!inside) {
            // prefix property: all remaining samples outside; only the forced
            // last sample (p_raw = 1) contributes, rgb zeroed outside.
            if (c < 1.0f) depth += (1.0f - c) * zlast;
            break;
        }

        // trilinear index/weights (align_corners=true: idx = u*(dim-1))
        float fx = fminf(fmaxf((px + 40.0f) / 80.0f * 199.0f, 0.0f), 199.0f);
        float fy = fminf(fmaxf((py + 40.0f) / 80.0f * 199.0f, 0.0f), 199.0f);
        float fz = fminf(fmaxf((pz + 1.0f)  / 6.4f  * 15.0f,  0.0f), 15.0f);
        int ix = min((int)fx, DX - 2);   // fx >= 0 so cast == floor
        int iy = min((int)fy, DY - 2);
        int iz = min((int)fz, DZ - 2);
        const float wx = fx - (float)ix, wy = fy - (float)iy, wz = fz - (float)iz;
        const float ux = 1.0f - wx, uy = 1.0f - wy, uz = 1.0f - wz;

        const float w000 = ux * uy * uz, w001 = ux * uy * wz;
        const float w010 = ux * wy * uz, w011 = ux * wy * wz;
        const float w100 = wx * uy * uz, w101 = wx * uy * wz;
        const float w110 = wx * wy * uz, w111 = wx * wy * wz;

        const int base = (ix * DY + iy) * DZ + iz;
        const int SX = DY * DZ;   // 3200
        const int SY = DZ;        // 16

        // density sample (accumulation order matches reference: 000..111)
        const float dens =
            vox[base]           * w000 + vox[base + 1]           * w001 +
            vox[base + SY]      * w010 + vox[base + SY + 1]      * w011 +
            vox[base + SX]      * w100 + vox[base + SX + 1]      * w101 +
            vox[base + SX + SY] * w110 + vox[base + SX + SY + 1] * w111;

        const float sig = 1.0f / (1.0f + __expf(-dens));

        const float newc = c + sig;
        const float p = fminf(newc, 1.0f) - fminf(c, 1.0f);

        depth += p * z;

        // rgb channels reuse the weights
        #pragma unroll
        for (int ch = 0; ch < 3; ++ch) {
            const float* g = rgbg + ch * GRID_N;
            const float v =
                g[base]           * w000 + g[base + 1]           * w001 +
                g[base + SY]      * w010 + g[base + SY + 1]      * w011 +
                g[base + SX]      * w100 + g[base + SX + 1]      * w101 +
                g[base + SX + SY] * w110 + g[base + SX + SY + 1] * w111;
            if (ch == 0) a0 += p * v;
            else if (ch == 1) a1 += p * v;
            else a2 += p * v;
        }

        c = newc;
        if (c >= 1.0f) break;   // saturated: every later probs[n] == 0
    }

    out[r]             = depth;
    out[R + 3 * r]     = a0;
    out[R + 3 * r + 1] = a1;
    out[R + 3 * r + 2] = a2;
}

extern "C" void kernel_launch(void* const* d_in, const int* in_sizes, int n_in,
                              void* d_out, int out_size, void* d_ws, size_t ws_size,
                              hipStream_t stream) {
    const float* ro   = (const float*)d_in[0];
    const float* rd   = (const float*)d_in[1];
    const float* vox  = (const float*)d_in[2];
    const float* rgbg = (const float*)d_in[3];
    float* out = (float*)d_out;

    const int R = in_sizes[0] / 3;               // 86400
    const int block = 256;
    const int grid = (R + block - 1) / block;

    nerf_march_kernel<<<grid, block, 0, stream>>>(ro, rd, vox, rgbg, out, R);
}